// Round 12
// baseline (590.354 us; speedup 1.0000x reference)
//
#include <hip/hip_runtime.h>
#include <hip/hip_bf16.h>

// Clockwork RNN, hierarchical decomposition + bf16 MFMA GEMMs.
// Round 12: in-kernel radix-2 fold. k_phase v8 = two independent interleaved
// A^2-chains (odd & even timesteps), A·u terms folded into each step's MFMAs:
//   h_{2j+1} = A^2 h_{2j-1} + A u_{2j}   + u_{2j+1}   (waves 0-1)
//   h_{2j}   = A^2 h_{2j-2} + A u_{2j-1} + u_{2j}     (waves 2-3; j=0: A hprev + u_0)
// waves 4,7: u producers (even/odd u-idx, 16-slot ring, counted vmcnt)
// waves 5,6: storers (odd/even hmod slots). No k_v/k_even launches.

#define TT 256
#define BB 128
#define INW 512
#define HH 128
#define MHW 1024

typedef __bf16 bf16x8 __attribute__((ext_vector_type(8)));
typedef __bf16 bf16x4 __attribute__((ext_vector_type(4)));
typedef float f32x4 __attribute__((ext_vector_type(4)));

__constant__ unsigned int c_hmod_off[8] = {
    0u, 4194304u, 6291456u, 7340032u, 7864320u, 8126464u, 8257536u, 8323072u};

__device__ __forceinline__ int active_thr(int t) {
    int ma = (t == 0) ? 8 : min(__ffs(t), 8);
    return ma * HH;
}

__device__ __forceinline__ unsigned short f2bf(float f) {
    union { float f; unsigned int u; } v{f};
    unsigned int r = v.u + 0x7FFFu + ((v.u >> 16) & 1u);  // RNE
    return (unsigned short)(r >> 16);
}
__device__ __forceinline__ unsigned int pack2(float lo, float hi) {
    return (unsigned int)f2bf(lo) | ((unsigned int)f2bf(hi) << 16);
}
__device__ __forceinline__ float bf2f(unsigned short u) {
    union { unsigned int i; float f; } v;
    v.i = ((unsigned int)u) << 16;
    return v.f;
}

__device__ __forceinline__ void gld_lds16(const float* g, char* l) {
    __builtin_amdgcn_global_load_lds(
        (const __attribute__((address_space(1))) void*)g,
        (__attribute__((address_space(3))) void*)l, 16, 0, 0);
}

#define TILE_B 16384  // one [128 rows][64 k] bf16 tile image in LDS

__device__ __forceinline__ void stage_load(float4 (&v)[8],
                                           const float* __restrict__ src,
                                           int stride, int tid) {
    int k4 = (tid & 15) * 4;
    int r0 = tid >> 4;
#pragma unroll
    for (int p = 0; p < 8; ++p)
        v[p] = *reinterpret_cast<const float4*>(src + (size_t)(p * 16 + r0) * stride + k4);
}

__device__ __forceinline__ void stage_write(char* dst, const float4 (&v)[8], int tid) {
    int k8 = (tid & 15) * 8;
    int r0 = tid >> 4;
#pragma unroll
    for (int p = 0; p < 8; ++p) {
        int row = p * 16 + r0;
        ushort4 b;
        b.x = f2bf(v[p].x); b.y = f2bf(v[p].y);
        b.z = f2bf(v[p].z); b.w = f2bf(v[p].w);
        int off = (row * 128 + k8) ^ ((row & 7) << 4);
        *reinterpret_cast<ushort4*>(dst + off) = b;
    }
}

__device__ __forceinline__ void stage_load_h16(uint4 (&v)[4],
                                               const unsigned short* __restrict__ src,
                                               int tid) {
    int k16 = (tid & 7) * 8;
    int r0 = tid >> 3;
#pragma unroll
    for (int p = 0; p < 4; ++p)
        v[p] = *reinterpret_cast<const uint4*>(src + (size_t)(p * 32 + r0) * HH + k16);
}
__device__ __forceinline__ void stage_write_h16(char* dst, const uint4 (&v)[4], int tid) {
    int k16 = (tid & 7) * 8;
    int r0 = tid >> 3;
#pragma unroll
    for (int p = 0; p < 4; ++p) {
        int row = p * 32 + r0;
        int off = (row * 128 + k16 * 2) ^ ((row & 7) << 4);
        *reinterpret_cast<uint4*>(dst + off) = v[p];
    }
}

__device__ __forceinline__ bf16x8 frag_ld(const char* tile, int row, int ks, int lane) {
    int off = (row * 128 + ks * 64 + (lane >> 4) * 16) ^ ((row & 7) << 4);
    return *reinterpret_cast<const bf16x8*>(tile + off);
}

__device__ __forceinline__ bf16x8 frag_ld_f32(const char* tile, int row, int ks, int g) {
    int off = ((row << 8) + ks * 128 + g * 32) ^ ((row & 7) << 4);
    f32x4 a = *reinterpret_cast<const f32x4*>(tile + off);
    f32x4 b = *reinterpret_cast<const f32x4*>(tile + (off ^ 16));
    bf16x8 u;
    u[0] = (__bf16)a[0]; u[1] = (__bf16)a[1]; u[2] = (__bf16)a[2]; u[3] = (__bf16)a[3];
    u[4] = (__bf16)b[0]; u[5] = (__bf16)b[1]; u[6] = (__bf16)b[2]; u[7] = (__bf16)b[3];
    return u;
}

__device__ __forceinline__ void mfma_tile(const char* sA, const char* sB,
                                          f32x4 (&acc)[4][4], int lane,
                                          int wr, int wc) {
#pragma unroll
    for (int ks = 0; ks < 2; ++ks) {
        bf16x8 fa[4], fb[4];
#pragma unroll
        for (int i = 0; i < 4; ++i) {
            fa[i] = frag_ld(sA, wr + i * 16 + (lane & 15), ks, lane);
            fb[i] = frag_ld(sB, wc + i * 16 + (lane & 15), ks, lane);
        }
#pragma unroll
        for (int i = 0; i < 4; ++i)
#pragma unroll
            for (int j = 0; j < 4; ++j)
                acc[i][j] = __builtin_amdgcn_mfma_f32_16x16x32_bf16(
                    fa[i], fb[j], acc[i][j], 0, 0, 0);
    }
}

// ---------------------------------------------------------------------------
// K_xw (unchanged R10): 1020 uniform blocks, gld_lds f32 staging.
// ---------------------------------------------------------------------------
__global__ __launch_bounds__(256) void k_xw(const float* __restrict__ x,
                                            const float* __restrict__ Wxh,
                                            const float* __restrict__ bh,
                                            float* __restrict__ xwb) {
    __shared__ char ldsW[2][32768];
    __shared__ char ldsX[2][16384];
    int id = blockIdx.x >> 1, half = blockIdx.x & 1;
    int rt = 0, rem = id;
    while (rem >= (256 >> rt)) { rem -= 256 >> rt; ++rt; }
    int t = rem << rt;

    int tid = threadIdx.x, lane = tid & 63, wid = tid >> 6;
    int l15 = lane & 15, g = lane >> 4;
    int wr = (wid >> 1) * 64, wc = (wid & 1) * 32;

    const float* gW[8];
    const float* gX[4];
    {
        int kb = (lane & 15) * 16;
#pragma unroll
        for (int i = 0; i < 8; ++i) {
            int row = i * 16 + wid * 4 + (lane >> 4);
            int kf = (kb ^ ((row & 7) << 4)) >> 2;
            gW[i] = Wxh + (size_t)(rt * 128 + row) * INW + kf;
        }
#pragma unroll
        for (int i = 0; i < 4; ++i) {
            int row = i * 16 + wid * 4 + (lane >> 4);
            int kf = (kb ^ ((row & 7) << 4)) >> 2;
            gX[i] = x + ((size_t)t * BB + half * 64 + row) * INW + kf;
        }
    }
#pragma unroll
    for (int i = 0; i < 8; ++i)
        gld_lds16(gW[i], &ldsW[0][0] + i * 4096 + wid * 1024);
#pragma unroll
    for (int i = 0; i < 4; ++i)
        gld_lds16(gX[i], &ldsX[0][0] + i * 4096 + wid * 1024);

    f32x4 acc[4][2] = {};
    for (int c = 0; c < 8; ++c) {
        int cur = c & 1;
        __syncthreads();
        if (c < 7) {
#pragma unroll
            for (int i = 0; i < 8; ++i)
                gld_lds16(gW[i] + (c + 1) * 64,
                          &ldsW[cur ^ 1][0] + i * 4096 + wid * 1024);
#pragma unroll
            for (int i = 0; i < 4; ++i)
                gld_lds16(gX[i] + (c + 1) * 64,
                          &ldsX[cur ^ 1][0] + i * 4096 + wid * 1024);
        }
#pragma unroll
        for (int ks = 0; ks < 2; ++ks) {
            bf16x8 fa[4], fb[2];
#pragma unroll
            for (int i = 0; i < 4; ++i)
                fa[i] = frag_ld_f32(&ldsW[cur][0], wr + i * 16 + l15, ks, g);
#pragma unroll
            for (int j = 0; j < 2; ++j)
                fb[j] = frag_ld_f32(&ldsX[cur][0], wc + j * 16 + l15, ks, g);
#pragma unroll
            for (int i = 0; i < 4; ++i)
#pragma unroll
                for (int j = 0; j < 2; ++j)
                    acc[i][j] = __builtin_amdgcn_mfma_f32_16x16x32_bf16(
                        fa[i], fb[j], acc[i][j], 0, 0, 0);
        }
    }
#pragma unroll
    for (int i = 0; i < 4; ++i) {
        int rbase = rt * 128 + wr + i * 16 + g * 4;
        float4 bias = *reinterpret_cast<const float4*>(&bh[rbase]);
#pragma unroll
        for (int j = 0; j < 2; ++j) {
            int b = half * 64 + wc + j * 16 + l15;
            float4 v = make_float4(acc[i][j][0] + bias.x, acc[i][j][1] + bias.y,
                                   acc[i][j][2] + bias.z, acc[i][j][3] + bias.w);
            *reinterpret_cast<float4*>(
                &xwb[(size_t)(t * BB + b) * MHW + rbase]) = v;
        }
    }
}

// ---------------------------------------------------------------------------
// K_a2: a2[mi] = A[mi]·A[mi] (f32, 128x128), one block per mi. (verified R11)
// ---------------------------------------------------------------------------
__global__ __launch_bounds__(256) void k_a2(const float* __restrict__ Whh,
                                            float* __restrict__ a2) {
    int mi = blockIdx.x;
    __shared__ char lds[2 * TILE_B];
    int tid = threadIdx.x, lane = tid & 63, wid = tid >> 6;
    int l15 = lane & 15, g = lane >> 4;
    int wr = (wid >> 1) * 64, wc = (wid & 1) * 64;
    const float* Ab = Whh + (size_t)(mi * HH) * MHW + mi * HH;
    f32x4 acc[4][4] = {};
    for (int c0 = 0; c0 < 128; c0 += 64) {
        float4 vA[8];
        stage_load(vA, Ab + c0, MHW, tid);
        __syncthreads();
        stage_write(lds, vA, tid);
        {
            int k4 = (tid & 15) * 4;
            int r0 = tid >> 4;
#pragma unroll
            for (int p = 0; p < 8; ++p) {
                int row = p * 16 + r0;
                ushort4 b;
                b.x = f2bf(Ab[(size_t)(c0 + k4 + 0) * MHW + row]);
                b.y = f2bf(Ab[(size_t)(c0 + k4 + 1) * MHW + row]);
                b.z = f2bf(Ab[(size_t)(c0 + k4 + 2) * MHW + row]);
                b.w = f2bf(Ab[(size_t)(c0 + k4 + 3) * MHW + row]);
                int off = (row * 128 + k4 * 2) ^ ((row & 7) << 4);
                *reinterpret_cast<ushort4*>(lds + TILE_B + off) = b;
            }
        }
        __syncthreads();
        mfma_tile(lds, lds + TILE_B, acc, lane, wr, wc);
    }
    float* dst = a2 + mi * 16384;
#pragma unroll
    for (int i = 0; i < 4; ++i) {
        int r0 = wr + i * 16 + g * 4;
#pragma unroll
        for (int jq = 0; jq < 4; ++jq) {
            int c = wc + jq * 16 + l15;
#pragma unroll
            for (int rr = 0; rr < 4; ++rr)
                dst[(size_t)(r0 + rr) * 128 + c] = acc[i][jq][rr];
        }
    }
}

// ---------------------------------------------------------------------------
// K_u (unchanged): xwb[t][b][mi*H+r] += sum_{j>mi} Whh[...]·h_j[b][c]
// ---------------------------------------------------------------------------
__global__ __launch_bounds__(256) void k_u(const float* __restrict__ Whh,
                                           const float* __restrict__ hprev,
                                           const unsigned short* __restrict__ hmod,
                                           float* __restrict__ xwb, int mi) {
    int k = blockIdx.x;
    int t = k << mi;
    __shared__ char lds[4 * TILE_B];
    int tid = threadIdx.x, lane = tid & 63, wid = tid >> 6;
    int wr = (wid >> 1) * 64, wc = (wid & 1) * 64;

    int ntile = 2 * (7 - mi);
    f32x4 acc[4][4] = {};

    if (k == 0) {
        auto srcs = [&](int tt, const float*& pa, const float*& ph) {
            int j = mi + 1 + (tt >> 1);
            int c0 = (tt & 1) * 64;
            pa = Whh + (size_t)(mi * HH) * MHW + j * HH + c0;
            ph = hprev + j * HH + c0;
        };
        float4 vA[8], vH[8];
        const float *pa, *ph;
        srcs(0, pa, ph);
        stage_load(vA, pa, MHW, tid);
        stage_load(vH, ph, MHW, tid);
        stage_write(lds, vA, tid);
        stage_write(lds + TILE_B, vH, tid);
        for (int tt = 0; tt < ntile; ++tt) {
            int cur = tt & 1;
            __syncthreads();
            if (tt + 1 < ntile) {
                srcs(tt + 1, pa, ph);
                stage_load(vA, pa, MHW, tid);
                stage_load(vH, ph, MHW, tid);
            }
            mfma_tile(lds + cur * 2 * TILE_B, lds + cur * 2 * TILE_B + TILE_B,
                      acc, lane, wr, wc);
            if (tt + 1 < ntile) {
                stage_write(lds + (cur ^ 1) * 2 * TILE_B, vA, tid);
                stage_write(lds + (cur ^ 1) * 2 * TILE_B + TILE_B, vH, tid);
            }
        }
    } else {
        auto srcs = [&](int tt, const float*& pa, const unsigned short*& ph) {
            int j = mi + 1 + (tt >> 1);
            int c0 = (tt & 1) * 64;
            pa = Whh + (size_t)(mi * HH) * MHW + j * HH + c0;
            int g = (t - 1) >> j;
            ph = hmod + c_hmod_off[j] + (size_t)g * BB * HH + c0;
        };
        float4 vA[8];
        uint4 vH[4];
        const float* pa;
        const unsigned short* ph;
        srcs(0, pa, ph);
        stage_load(vA, pa, MHW, tid);
        stage_load_h16(vH, ph, tid);
        stage_write(lds, vA, tid);
        stage_write_h16(lds + TILE_B, vH, tid);
        for (int tt = 0; tt < ntile; ++tt) {
            int cur = tt & 1;
            __syncthreads();
            if (tt + 1 < ntile) {
                srcs(tt + 1, pa, ph);
                stage_load(vA, pa, MHW, tid);
                stage_load_h16(vH, ph, tid);
            }
            mfma_tile(lds + cur * 2 * TILE_B, lds + cur * 2 * TILE_B + TILE_B,
                      acc, lane, wr, wc);
            if (tt + 1 < ntile) {
                stage_write(lds + (cur ^ 1) * 2 * TILE_B, vA, tid);
                stage_write_h16(lds + (cur ^ 1) * 2 * TILE_B + TILE_B, vH, tid);
            }
        }
    }
#pragma unroll
    for (int i = 0; i < 4; ++i) {
        int rbase = wr + i * 16 + (lane >> 4) * 4;
#pragma unroll
        for (int j = 0; j < 4; ++j) {
            int b = wc + j * 16 + (lane & 15);
            float4* p = reinterpret_cast<float4*>(
                &xwb[(size_t)(t * BB + b) * MHW + mi * HH + rbase]);
            float4 v = *p;
            v.x += acc[i][j][0]; v.y += acc[i][j][1];
            v.z += acc[i][j][2]; v.w += acc[i][j][3];
            *p = v;
        }
    }
}

// ---------------------------------------------------------------------------
// K_phase v8: in-kernel fold, 8 waves (512 thr), 8 blocks x 16 batches.
//   wid 0-1: odd chain  o_K = A^2 o_{K-1} + A u_{2K}   + u_{2K+1}
//   wid 2-3: even chain e_K = A^2 e_{K-1} + A u_{2K-1} + u_{2K}; e_0 = A hprev + u_0
//   wid 4:   producer even u-idx (vmcnt 40); wid 7: producer odd u-idx (vmcnt 32)
//   wid 5:   storer odd hmod slots; wid 6: storer even slots.
// ---------------------------------------------------------------------------
#define SYNC_LDS()                                              \
    do {                                                        \
        asm volatile("s_waitcnt lgkmcnt(0)" ::: "memory");      \
        __builtin_amdgcn_sched_barrier(0);                      \
        __builtin_amdgcn_s_barrier();                           \
        __builtin_amdgcn_sched_barrier(0);                      \
    } while (0)
#define SYNC_VM(NS)                                             \
    do {                                                        \
        asm volatile("s_waitcnt vmcnt(" NS ")" ::: "memory");   \
        __builtin_amdgcn_sched_barrier(0);                      \
        __builtin_amdgcn_s_barrier();                           \
        __builtin_amdgcn_sched_barrier(0);                      \
    } while (0)

__global__ __launch_bounds__(512) void k_phase(const float* __restrict__ a2,
                                               const float* __restrict__ Whh,
                                               const float* __restrict__ hprev,
                                               const float* __restrict__ xwb,
                                               unsigned short* __restrict__ hmod,
                                               int mi) {
    int b0 = blockIdx.x * 16;
    int tid = threadIdx.x, lane = tid & 63, wid = tid >> 6;
    int l15 = lane & 15, g = lane >> 4;
    __shared__ char sHo[2][4096];
    __shared__ char sHe[2][4096];
    __shared__ char sU[16][8192];  // u ring, slot = u_idx & 15, linear f32
    int Tm = TT >> mi, Tm2 = Tm >> 1;

    if (wid < 4) {
        // ================= compute waves (both chains) =================
        int w = wid & 1;
        bool is_odd = wid < 2;
        char(*sH)[4096] = is_odd ? sHo : sHe;

        bf16x8 A2f[4][4], A1f[4][4];
        {
            const float* Ab2 = a2 + mi * 16384;
            const float* Ab1 = Whh + (size_t)(mi * HH) * MHW + mi * HH;
#pragma unroll
            for (int mm = 0; mm < 4; ++mm) {
                const float* r2 = Ab2 + (size_t)(64 * w + mm * 16 + l15) * 128;
                const float* r1 = Ab1 + (size_t)(64 * w + mm * 16 + l15) * MHW;
#pragma unroll
                for (int kf = 0; kf < 4; ++kf) {
                    float4 a0 = *reinterpret_cast<const float4*>(r2 + kf * 32 + g * 8);
                    float4 a1 = *reinterpret_cast<const float4*>(r2 + kf * 32 + g * 8 + 4);
                    float4 b0v = *reinterpret_cast<const float4*>(r1 + kf * 32 + g * 8);
                    float4 b1v = *reinterpret_cast<const float4*>(r1 + kf * 32 + g * 8 + 4);
                    bf16x8 u2, u1;
                    u2[0] = (__bf16)a0.x; u2[1] = (__bf16)a0.y;
                    u2[2] = (__bf16)a0.z; u2[3] = (__bf16)a0.w;
                    u2[4] = (__bf16)a1.x; u2[5] = (__bf16)a1.y;
                    u2[6] = (__bf16)a1.z; u2[7] = (__bf16)a1.w;
                    u1[0] = (__bf16)b0v.x; u1[1] = (__bf16)b0v.y;
                    u1[2] = (__bf16)b0v.z; u1[3] = (__bf16)b0v.w;
                    u1[4] = (__bf16)b1v.x; u1[5] = (__bf16)b1v.y;
                    u1[6] = (__bf16)b1v.z; u1[7] = (__bf16)b1v.w;
                    A2f[mm][kf] = u2;
                    A1f[mm][kf] = u1;
                }
            }
        }
        // odd waves init sHo[0] = hprev; even waves load hprev frags.
        bf16x8 hpf[4];
        if (is_odd) {
#pragma unroll
            for (int p = 0; p < 2; ++p) {
                int tt = tid + p * 128;  // tid in 0..127
                int b = tt >> 4, r8 = (tt & 15) * 8;
                const float* hp = hprev + (size_t)(b0 + b) * MHW + mi * HH + r8;
                float4 v0 = *reinterpret_cast<const float4*>(hp);
                float4 v1 = *reinterpret_cast<const float4*>(hp + 4);
                uint4 pk;
                pk.x = pack2(v0.x, v0.y); pk.y = pack2(v0.z, v0.w);
                pk.z = pack2(v1.x, v1.y); pk.w = pack2(v1.z, v1.w);
                int off = (b * 256 + r8 * 2) ^ ((b & 7) << 4);
                *reinterpret_cast<uint4*>(&sHo[0][0] + off) = pk;
            }
        } else {
            const float* hp = hprev + (size_t)(b0 + l15) * MHW + mi * HH;
#pragma unroll
            for (int kf = 0; kf < 4; ++kf) {
                float4 v0 = *reinterpret_cast<const float4*>(hp + kf * 32 + g * 8);
                float4 v1 = *reinterpret_cast<const float4*>(hp + kf * 32 + g * 8 + 4);
                bf16x8 u;
                u[0] = (__bf16)v0.x; u[1] = (__bf16)v0.y;
                u[2] = (__bf16)v0.z; u[3] = (__bf16)v0.w;
                u[4] = (__bf16)v1.x; u[5] = (__bf16)v1.y;
                u[6] = (__bf16)v1.z; u[7] = (__bf16)v1.w;
                hpf[kf] = u;
            }
        }
        int roff[4], woff[4], uoff[4], buoff[4];
#pragma unroll
        for (int kf = 0; kf < 4; ++kf) {
            roff[kf] = (l15 * 256 + kf * 64 + g * 16) ^ ((l15 & 7) << 4);
            buoff[kf] = (kf * 8 + g * 2) * 256 + l15 * 16;
        }
#pragma unroll
        for (int mm = 0; mm < 4; ++mm) {
            woff[mm] = (l15 * 256 + (64 * w + mm * 16 + g * 4) * 2) ^ ((l15 & 7) << 4);
            uoff[mm] = (16 * w + 4 * mm + g) * 256 + l15 * 16;
        }
        SYNC_LDS();

        int K0 = 0;
        if (!is_odd) {
            // even chain step 0: e_0 = A·hprev + u_0
            const char* ubS = &sU[0][0];
            f32x4 acc[4], acc2[4];
#pragma unroll
            for (int mm = 0; mm < 4; ++mm) {
                acc[mm] = *reinterpret_cast<const f32x4*>(ubS + uoff[mm]);
                acc2[mm] = (f32x4){0.f, 0.f, 0.f, 0.f};
            }
#pragma unroll
            for (int mm = 0; mm < 4; ++mm) {
                acc[mm] = __builtin_amdgcn_mfma_f32_16x16x32_bf16(
                    A1f[mm][0], hpf[0], acc[mm], 0, 0, 0);
                acc2[mm] = __builtin_amdgcn_mfma_f32_16x16x32_bf16(
                    A1f[mm][2], hpf[2], acc2[mm], 0, 0, 0);
                acc[mm] = __builtin_amdgcn_mfma_f32_16x16x32_bf16(
                    A1f[mm][1], hpf[1], acc[mm], 0, 0, 0);
                acc2[mm] = __builtin_amdgcn_mfma_f32_16x16x32_bf16(
                    A1f[mm][3], hpf[3], acc2[mm], 0, 0, 0);
            }
#pragma unroll
            for (int mm = 0; mm < 4; ++mm) {
                acc[mm] += acc2[mm];
                bf16x4 pk;
                pk[0] = (__bf16)acc[mm][0]; pk[1] = (__bf16)acc[mm][1];
                pk[2] = (__bf16)acc[mm][2]; pk[3] = (__bf16)acc[mm][3];
                *reinterpret_cast<bf16x4*>(&sHe[1][0] + woff[mm]) = pk;
            }
            SYNC_LDS();
            K0 = 1;
        }
        for (int K = K0; K < Tm2; ++K) {
            int cur = K & 1;
            int seed_idx = is_odd ? (2 * K + 1) : (2 * K);
            int frag_idx = is_odd ? (2 * K) : (2 * K - 1);
            const char* ubS = &sU[seed_idx & 15][0];
            const char* ubF = &sU[frag_idx & 15][0];
            f32x4 acc[4], acc2[4];
#pragma unroll
            for (int mm = 0; mm < 4; ++mm) {
                acc[mm] = *reinterpret_cast<const f32x4*>(ubS + uoff[mm]);
                acc2[mm] = (f32x4){0.f, 0.f, 0.f, 0.f};
            }
            bf16x8 Bh[4], Bu[4];
#pragma unroll
            for (int kf = 0; kf < 4; ++kf) {
                Bh[kf] = *reinterpret_cast<const bf16x8*>(&sH[cur][0] + roff[kf]);
                f32x4 ua = *reinterpret_cast<const f32x4*>(ubF + buoff[kf]);
                f32x4 ub = *reinterpret_cast<const f32x4*>(ubF + buoff[kf] + 256);
                bf16x8 u;
                u[0] = (__bf16)ua[0]; u[1] = (__bf16)ua[1];
                u[2] = (__bf16)ua[2]; u[3] = (__bf16)ua[3];
                u[4] = (__bf16)ub[0]; u[5] = (__bf16)ub[1];
                u[6] = (__bf16)ub[2]; u[7] = (__bf16)ub[3];
                Bu[kf] = u;
            }
#pragma unroll
            for (int mm = 0; mm < 4; ++mm) {
                acc[mm] = __builtin_amdgcn_mfma_f32_16x16x32_bf16(
                    A2f[mm][0], Bh[0], acc[mm], 0, 0, 0);
                acc2[mm] = __builtin_amdgcn_mfma_f32_16x16x32_bf16(
                    A2f[mm][2], Bh[2], acc2[mm], 0, 0, 0);
                acc[mm] = __builtin_amdgcn_mfma_f32_16x16x32_bf16(
                    A2f[mm][1], Bh[1], acc[mm], 0, 0, 0);
                acc2[mm] = __builtin_amdgcn_mfma_f32_16x16x32_bf16(
                    A2f[mm][3], Bh[3], acc2[mm], 0, 0, 0);
                acc[mm] = __builtin_amdgcn_mfma_f32_16x16x32_bf16(
                    A1f[mm][0], Bu[0], acc[mm], 0, 0, 0);
                acc2[mm] = __builtin_amdgcn_mfma_f32_16x16x32_bf16(
                    A1f[mm][2], Bu[2], acc2[mm], 0, 0, 0);
                acc[mm] = __builtin_amdgcn_mfma_f32_16x16x32_bf16(
                    A1f[mm][1], Bu[1], acc[mm], 0, 0, 0);
                acc2[mm] = __builtin_amdgcn_mfma_f32_16x16x32_bf16(
                    A1f[mm][3], Bu[3], acc2[mm], 0, 0, 0);
            }
#pragma unroll
            for (int mm = 0; mm < 4; ++mm) {
                acc[mm] += acc2[mm];
                bf16x4 pk;
                pk[0] = (__bf16)acc[mm][0]; pk[1] = (__bf16)acc[mm][1];
                pk[2] = (__bf16)acc[mm][2]; pk[3] = (__bf16)acc[mm][3];
                *reinterpret_cast<bf16x4*>(&sH[cur ^ 1][0] + woff[mm]) = pk;
            }
            SYNC_LDS();
        }
    } else if (wid == 4 || wid == 7) {
        // ================= producers =================
        const float* ubase = xwb + (size_t)(b0 + l15) * MHW + mi * HH + g * 4;
        auto fill = [&](int k) {
            int kk = min(k, Tm - 1);
            const float* pt = ubase + ((size_t)(kk << mi)) * BB * MHW;
            char* dst = &sU[kk & 15][0];
#pragma unroll
            for (int p = 0; p < 8; ++p)
                gld_lds16(pt + p * 16, dst + p * 1024);
        };
        if (wid == 4) {  // even u-idx
            fill(0); fill(2); fill(4); fill(6); fill(8); fill(10);
            SYNC_VM("40");
            for (int K = 0; K < Tm2; ++K) {
                fill(2 * K + 12);
                SYNC_VM("40");
            }
        } else {  // odd u-idx
            fill(1); fill(3); fill(5); fill(7); fill(9);
            SYNC_VM("32");
            for (int K = 0; K < Tm2; ++K) {
                fill(2 * K + 11);
                SYNC_VM("32");
            }
        }
        asm volatile("s_waitcnt vmcnt(0)" ::: "memory");
    } else {
        // ================= storers (wid 5: odd slots, wid 6: even) =================
        bool so = (wid == 5);
        const char(*sH)[4096] = so ? sHo : sHe;
        int bq = lane >> 2;
        int rr = (lane & 3) * 32;
        unsigned short* hm = hmod + c_hmod_off[mi] + (size_t)(b0 + bq) * HH + rr;
        int soff[4];
#pragma unroll
        for (int c = 0; c < 4; ++c)
            soff[c] = (bq * 256 + (rr + c * 8) * 2) ^ ((bq & 7) << 4);
        SYNC_LDS();
        for (int K = 0; K < Tm2; ++K) {
            if (K >= 1) {
                uint4 h[4];
#pragma unroll
                for (int c = 0; c < 4; ++c)
                    h[c] = *reinterpret_cast<const uint4*>(&sH[K & 1][0] + soff[c]);
                int slot = so ? (2 * K - 1) : (2 * K - 2);
                unsigned short* dst = hm + (size_t)slot * BB * HH;
#pragma unroll
                for (int c = 0; c < 4; ++c)
                    *reinterpret_cast<uint4*>(dst + c * 8) = h[c];
            }
            SYNC_LDS();
        }
        {
            uint4 h[4];
#pragma unroll
            for (int c = 0; c < 4; ++c)
                h[c] = *reinterpret_cast<const uint4*>(&sH[Tm2 & 1][0] + soff[c]);
            int slot = so ? (2 * Tm2 - 1) : (2 * Tm2 - 2);
            unsigned short* dst = hm + (size_t)slot * BB * HH;
#pragma unroll
            for (int c = 0; c < 4; ++c)
                *reinterpret_cast<uint4*>(dst + c * 8) = h[c];
        }
    }
}

// ---------------------------------------------------------------------------
// K_out: out[t][b][j*H + h] = bf2f(Hmod[j][t>>j][b][h]); h_last for t==T-1
// ---------------------------------------------------------------------------
__global__ __launch_bounds__(256) void k_out(const unsigned short* __restrict__ hmod,
                                             float* __restrict__ out) {
    int b = blockIdx.x, t = blockIdx.y;
    int tid = threadIdx.x;
    int i = tid * 4;
    int j = i >> 7;
    int k = t >> j;
    ushort4 h = *reinterpret_cast<const ushort4*>(
        &hmod[c_hmod_off[j] + ((size_t)k * BB + b) * HH + (i & 127)]);
    float4 v = make_float4(bf2f(h.x), bf2f(h.y), bf2f(h.z), bf2f(h.w));
    *reinterpret_cast<float4*>(&out[((size_t)t * BB + b) * MHW + i]) = v;
    if (t == TT - 1) {
        *reinterpret_cast<float4*>(
            &out[(size_t)TT * BB * MHW + (size_t)b * MHW + i]) = v;
    }
}

// ---------------------------------------------------------------------------
extern "C" void kernel_launch(void* const* d_in, const int* in_sizes, int n_in,
                              void* d_out, int out_size, void* d_ws, size_t ws_size,
                              hipStream_t stream) {
    const float* x = (const float*)d_in[0];
    const float* hprev = (const float*)d_in[1];
    const float* Wxh = (const float*)d_in[2];
    const float* Whh = (const float*)d_in[3];
    const float* bh = (const float*)d_in[4];
    float* out = (float*)d_out;

    float* xwb = out;                              // scratch in d_out
    unsigned short* hmod = (unsigned short*)d_ws;  // bf16, 16.7 MB
    float* a2 = (float*)((char*)d_ws + 16711680);  // 512 KB

    k_xw<<<dim3(1020), 256, 0, stream>>>(x, Wxh, bh, xwb);
    k_a2<<<dim3(8), 256, 0, stream>>>(Whh, a2);

    for (int mi = 7; mi >= 0; --mi) {
        if (mi < 7)
            k_u<<<dim3(TT >> mi), 256, 0, stream>>>(Whh, hprev, hmod, xwb, mi);
        k_phase<<<8, 512, 0, stream>>>(a2, Whh, hprev, xwb, hmod, mi);
    }

    k_out<<<dim3(128, 256), 256, 0, stream>>>(hmod, out);
}

// Round 13
// 404.112 us; speedup vs baseline: 1.4609x; 1.4609x over previous
//
#include <hip/hip_runtime.h>
#include <hip/hip_bf16.h>

// Clockwork RNN, hierarchical decomposition + bf16 MFMA GEMMs.
// Round 13: revert k_phase to R10 v6 (best measured); port k_u to the
// proven gld_lds staging structure (R10 k_xw): A-panel f32 + H-operand
// (bf16 hmod / f32 hprev) staged via global_load_lds with pre-swizzled
// sources, f32->bf16 convert fused into fragment reads. k_a2 dropped.

#define TT 256
#define BB 128
#define INW 512
#define HH 128
#define MHW 1024

typedef __bf16 bf16x8 __attribute__((ext_vector_type(8)));
typedef __bf16 bf16x4 __attribute__((ext_vector_type(4)));
typedef float f32x4 __attribute__((ext_vector_type(4)));

__constant__ unsigned int c_hmod_off[8] = {
    0u, 4194304u, 6291456u, 7340032u, 7864320u, 8126464u, 8257536u, 8323072u};

__device__ __forceinline__ int active_thr(int t) {
    int ma = (t == 0) ? 8 : min(__ffs(t), 8);
    return ma * HH;
}

__device__ __forceinline__ unsigned short f2bf(float f) {
    union { float f; unsigned int u; } v{f};
    unsigned int r = v.u + 0x7FFFu + ((v.u >> 16) & 1u);  // RNE
    return (unsigned short)(r >> 16);
}
__device__ __forceinline__ unsigned int pack2(float lo, float hi) {
    return (unsigned int)f2bf(lo) | ((unsigned int)f2bf(hi) << 16);
}
__device__ __forceinline__ float bf2f(unsigned short u) {
    union { unsigned int i; float f; } v;
    v.i = ((unsigned int)u) << 16;
    return v.f;
}

__device__ __forceinline__ void gld_lds16(const void* g, char* l) {
    __builtin_amdgcn_global_load_lds(
        (const __attribute__((address_space(1))) void*)g,
        (__attribute__((address_space(3))) void*)l, 16, 0, 0);
}

// Read one 16x32 bf16 fragment (8 bf16) from a swizzled bf16 tile ([rows][64] bf16).
__device__ __forceinline__ bf16x8 frag_ld(const char* tile, int row, int ks, int lane) {
    int off = (row * 128 + ks * 64 + (lane >> 4) * 16) ^ ((row & 7) << 4);
    return *reinterpret_cast<const bf16x8*>(tile + off);
}

// Read one fragment from a swizzled *f32* tile ([rows][64] f32, 256B/row),
// convert to bf16x8 (compiler emits packed cvt).
__device__ __forceinline__ bf16x8 frag_ld_f32(const char* tile, int row, int ks, int g) {
    int off = ((row << 8) + ks * 128 + g * 32) ^ ((row & 7) << 4);
    f32x4 a = *reinterpret_cast<const f32x4*>(tile + off);
    f32x4 b = *reinterpret_cast<const f32x4*>(tile + (off ^ 16));
    bf16x8 u;
    u[0] = (__bf16)a[0]; u[1] = (__bf16)a[1]; u[2] = (__bf16)a[2]; u[3] = (__bf16)a[3];
    u[4] = (__bf16)b[0]; u[5] = (__bf16)b[1]; u[6] = (__bf16)b[2]; u[7] = (__bf16)b[3];
    return u;
}

// ---------------------------------------------------------------------------
// K_xw (unchanged R10): 1020 uniform blocks = 510 active (t, rt) x 2 halves.
// gld_lds f32 staging, pre-swizzled sources, cvt-on-read fragments.
// ---------------------------------------------------------------------------
__global__ __launch_bounds__(256) void k_xw(const float* __restrict__ x,
                                            const float* __restrict__ Wxh,
                                            const float* __restrict__ bh,
                                            float* __restrict__ xwb) {
    __shared__ char ldsW[2][32768];
    __shared__ char ldsX[2][16384];
    int id = blockIdx.x >> 1, half = blockIdx.x & 1;
    int rt = 0, rem = id;
    while (rem >= (256 >> rt)) { rem -= 256 >> rt; ++rt; }
    int t = rem << rt;

    int tid = threadIdx.x, lane = tid & 63, wid = tid >> 6;
    int l15 = lane & 15, g = lane >> 4;
    int wr = (wid >> 1) * 64, wc = (wid & 1) * 32;

    const float* gW[8];
    const float* gX[4];
    {
        int kb = (lane & 15) * 16;
#pragma unroll
        for (int i = 0; i < 8; ++i) {
            int row = i * 16 + wid * 4 + (lane >> 4);
            int kf = (kb ^ ((row & 7) << 4)) >> 2;
            gW[i] = Wxh + (size_t)(rt * 128 + row) * INW + kf;
        }
#pragma unroll
        for (int i = 0; i < 4; ++i) {
            int row = i * 16 + wid * 4 + (lane >> 4);
            int kf = (kb ^ ((row & 7) << 4)) >> 2;
            gX[i] = x + ((size_t)t * BB + half * 64 + row) * INW + kf;
        }
    }
#pragma unroll
    for (int i = 0; i < 8; ++i)
        gld_lds16(gW[i], &ldsW[0][0] + i * 4096 + wid * 1024);
#pragma unroll
    for (int i = 0; i < 4; ++i)
        gld_lds16(gX[i], &ldsX[0][0] + i * 4096 + wid * 1024);

    f32x4 acc[4][2] = {};
    for (int c = 0; c < 8; ++c) {
        int cur = c & 1;
        __syncthreads();
        if (c < 7) {
#pragma unroll
            for (int i = 0; i < 8; ++i)
                gld_lds16(gW[i] + (c + 1) * 64,
                          &ldsW[cur ^ 1][0] + i * 4096 + wid * 1024);
#pragma unroll
            for (int i = 0; i < 4; ++i)
                gld_lds16(gX[i] + (c + 1) * 64,
                          &ldsX[cur ^ 1][0] + i * 4096 + wid * 1024);
        }
#pragma unroll
        for (int ks = 0; ks < 2; ++ks) {
            bf16x8 fa[4], fb[2];
#pragma unroll
            for (int i = 0; i < 4; ++i)
                fa[i] = frag_ld_f32(&ldsW[cur][0], wr + i * 16 + l15, ks, g);
#pragma unroll
            for (int j = 0; j < 2; ++j)
                fb[j] = frag_ld_f32(&ldsX[cur][0], wc + j * 16 + l15, ks, g);
#pragma unroll
            for (int i = 0; i < 4; ++i)
#pragma unroll
                for (int j = 0; j < 2; ++j)
                    acc[i][j] = __builtin_amdgcn_mfma_f32_16x16x32_bf16(
                        fa[i], fb[j], acc[i][j], 0, 0, 0);
        }
    }
#pragma unroll
    for (int i = 0; i < 4; ++i) {
        int rbase = rt * 128 + wr + i * 16 + g * 4;
        float4 bias = *reinterpret_cast<const float4*>(&bh[rbase]);
#pragma unroll
        for (int j = 0; j < 2; ++j) {
            int b = half * 64 + wc + j * 16 + l15;
            float4 v = make_float4(acc[i][j][0] + bias.x, acc[i][j][1] + bias.y,
                                   acc[i][j][2] + bias.z, acc[i][j][3] + bias.w);
            *reinterpret_cast<float4*>(
                &xwb[(size_t)(t * BB + b) * MHW + rbase]) = v;
        }
    }
}

// ---------------------------------------------------------------------------
// K_u v2: xwb[t][b][mi*H+r] += sum_{j>mi} Whh[mi*H+r][j*H+c] * h_j[b][c]
// gld_lds staging: A f32 [128r][64c] (32KB dbuf), H = hprev f32 (32KB tiles)
// or hmod bf16 (16KB tiles). One block per t; ntile = 2*(7-mi) chunks.
// ---------------------------------------------------------------------------
__global__ __launch_bounds__(256) void k_u(const float* __restrict__ Whh,
                                           const float* __restrict__ hprev,
                                           const unsigned short* __restrict__ hmod,
                                           float* __restrict__ xwb, int mi) {
    __shared__ char lds[131072];  // A0 A1 | H0 H1
    char* ldsA0 = lds;
    char* ldsA1 = lds + 32768;
    char* ldsH0 = lds + 65536;
    char* ldsH1 = lds + 98304;
    int k = blockIdx.x;
    int t = k << mi;
    int tid = threadIdx.x, lane = tid & 63, wid = tid >> 6;
    int l15 = lane & 15, g = lane >> 4;
    int wr = (wid >> 1) * 64, wc = (wid & 1) * 64;
    int ntile = 2 * (7 - mi);

    // A sources: per-thread 8 pre-swizzled row pointers (chunk adds j*HH+c0).
    const float* gA[8];
    {
        int kb = l15 * 16;
#pragma unroll
        for (int i = 0; i < 8; ++i) {
            int row = i * 16 + wid * 4 + g;
            int kf = (kb ^ ((row & 7) << 4)) >> 2;
            gA[i] = Whh + (size_t)(mi * HH + row) * MHW + kf;
        }
    }
    f32x4 acc[4][4] = {};

    if (k == 0) {
        // H = hprev (f32, row stride MHW)
        const float* gH[8];
        {
            int kb = l15 * 16;
#pragma unroll
            for (int i = 0; i < 8; ++i) {
                int row = i * 16 + wid * 4 + g;
                int kf = (kb ^ ((row & 7) << 4)) >> 2;
                gH[i] = hprev + (size_t)row * MHW + kf;
            }
        }
        auto stage = [&](int tt, char* dA, char* dH) {
            int j = mi + 1 + (tt >> 1), c0 = (tt & 1) * 64;
            int off = j * HH + c0;
#pragma unroll
            for (int i = 0; i < 8; ++i)
                gld_lds16(gA[i] + off, dA + i * 4096 + wid * 1024);
#pragma unroll
            for (int i = 0; i < 8; ++i)
                gld_lds16(gH[i] + off, dH + i * 4096 + wid * 1024);
        };
        stage(0, ldsA0, ldsH0);
        for (int tt = 0; tt < ntile; ++tt) {
            int cur = tt & 1;
            __syncthreads();
            if (tt + 1 < ntile)
                stage(tt + 1, cur ? ldsA0 : ldsA1, cur ? ldsH0 : ldsH1);
            const char* sA = cur ? ldsA1 : ldsA0;
            const char* sH = cur ? ldsH1 : ldsH0;
#pragma unroll
            for (int ks = 0; ks < 2; ++ks) {
                bf16x8 fa[4], fb[4];
#pragma unroll
                for (int i = 0; i < 4; ++i) {
                    fa[i] = frag_ld_f32(sA, wr + i * 16 + l15, ks, g);
                    fb[i] = frag_ld_f32(sH, wc + i * 16 + l15, ks, g);
                }
#pragma unroll
                for (int i = 0; i < 4; ++i)
#pragma unroll
                    for (int jj = 0; jj < 4; ++jj)
                        acc[i][jj] = __builtin_amdgcn_mfma_f32_16x16x32_bf16(
                            fa[i], fb[jj], acc[i][jj], 0, 0, 0);
            }
        }
    } else {
        // H = hmod (bf16, row stride HH); per-thread 4 pre-swizzled offsets.
        size_t hoff[4];
        {
            int cb = ((lane & 7) * 16) ^ ((lane >> 3) << 4);  // byte, pre-swz
#pragma unroll
            for (int p = 0; p < 4; ++p) {
                int row = p * 32 + wid * 8 + (lane >> 3);
                hoff[p] = (size_t)row * HH + (cb >> 1);
            }
        }
        auto stage = [&](int tt, char* dA, char* dH) {
            int j = mi + 1 + (tt >> 1), c0 = (tt & 1) * 64;
            int offA = j * HH + c0;
#pragma unroll
            for (int i = 0; i < 8; ++i)
                gld_lds16(gA[i] + offA, dA + i * 4096 + wid * 1024);
            const unsigned short* hb =
                hmod + c_hmod_off[j] + (size_t)((t - 1) >> j) * BB * HH + c0;
#pragma unroll
            for (int p = 0; p < 4; ++p)
                gld_lds16(hb + hoff[p], dH + p * 4096 + wid * 1024);
        };
        stage(0, ldsA0, ldsH0);
        for (int tt = 0; tt < ntile; ++tt) {
            int cur = tt & 1;
            __syncthreads();
            if (tt + 1 < ntile)
                stage(tt + 1, cur ? ldsA0 : ldsA1, cur ? ldsH0 : ldsH1);
            const char* sA = cur ? ldsA1 : ldsA0;
            const char* sH = cur ? ldsH1 : ldsH0;
#pragma unroll
            for (int ks = 0; ks < 2; ++ks) {
                bf16x8 fa[4], fb[4];
#pragma unroll
                for (int i = 0; i < 4; ++i) {
                    fa[i] = frag_ld_f32(sA, wr + i * 16 + l15, ks, g);
                    fb[i] = frag_ld(sH, wc + i * 16 + l15, ks, lane);
                }
#pragma unroll
                for (int i = 0; i < 4; ++i)
#pragma unroll
                    for (int jj = 0; jj < 4; ++jj)
                        acc[i][jj] = __builtin_amdgcn_mfma_f32_16x16x32_bf16(
                            fa[i], fb[jj], acc[i][jj], 0, 0, 0);
            }
        }
    }
#pragma unroll
    for (int i = 0; i < 4; ++i) {
        int rbase = wr + i * 16 + g * 4;
#pragma unroll
        for (int j = 0; j < 4; ++j) {
            int b = wc + j * 16 + l15;
            float4* p = reinterpret_cast<float4*>(
                &xwb[(size_t)(t * BB + b) * MHW + mi * HH + rbase]);
            float4 v = *p;
            v.x += acc[i][j][0]; v.y += acc[i][j][1];
            v.z += acc[i][j][2]; v.w += acc[i][j][3];
            *p = v;
        }
    }
}

// ---------------------------------------------------------------------------
// K_phase v6 (R10, verified): wave-specialized MFMA scan. 8 blocks x 16
// batches, 256 thr = waves {0,1}: compute, 2: u-producer, 3: h-storer.
// ---------------------------------------------------------------------------
#define SYNC_LDS()                                              \
    do {                                                        \
        asm volatile("s_waitcnt lgkmcnt(0)" ::: "memory");      \
        __builtin_amdgcn_sched_barrier(0);                      \
        __builtin_amdgcn_s_barrier();                           \
        __builtin_amdgcn_sched_barrier(0);                      \
    } while (0)
#define SYNC_VM24()                                             \
    do {                                                        \
        asm volatile("s_waitcnt vmcnt(24)" ::: "memory");       \
        __builtin_amdgcn_sched_barrier(0);                      \
        __builtin_amdgcn_s_barrier();                           \
        __builtin_amdgcn_sched_barrier(0);                      \
    } while (0)

__global__ __launch_bounds__(256) void k_phase(const float* __restrict__ Whh,
                                               const float* __restrict__ hprev,
                                               const float* __restrict__ xwb,
                                               unsigned short* __restrict__ hmod,
                                               int mi) {
    int b0 = blockIdx.x * 16;
    int tid = threadIdx.x, lane = tid & 63, wid = tid >> 6;
    int l15 = lane & 15, g = lane >> 4;
    __shared__ char sH[2][4096];   // [buf][b][r] bf16, swizzled
    __shared__ char sU[8][8192];   // u ring: [slot][r/4][b][4xf32], linear
    int Tm = TT >> mi;

    if (wid < 2) {
        // ================= compute waves =================
        bf16x8 Af[4][4];
        {
            const float* Ab = Whh + (size_t)(mi * HH) * MHW + mi * HH;
#pragma unroll
            for (int mm = 0; mm < 4; ++mm) {
                const float* row = Ab + (size_t)(64 * wid + mm * 16 + l15) * MHW;
#pragma unroll
                for (int kf = 0; kf < 4; ++kf) {
                    float4 v0 = *reinterpret_cast<const float4*>(row + kf * 32 + g * 8);
                    float4 v1 = *reinterpret_cast<const float4*>(row + kf * 32 + g * 8 + 4);
                    bf16x8 u;
                    u[0] = (__bf16)v0.x; u[1] = (__bf16)v0.y;
                    u[2] = (__bf16)v0.z; u[3] = (__bf16)v0.w;
                    u[4] = (__bf16)v1.x; u[5] = (__bf16)v1.y;
                    u[6] = (__bf16)v1.z; u[7] = (__bf16)v1.w;
                    Af[mm][kf] = u;
                }
            }
        }
        // initial H into buf 0 (tid 0..127 cover 16 batches x 128 rows)
#pragma unroll
        for (int p = 0; p < 2; ++p) {
            int tt = tid + p * 128;
            int b = tt >> 4, r8 = (tt & 15) * 8;
            const float* hp = hprev + (size_t)(b0 + b) * MHW + mi * HH + r8;
            float4 v0 = *reinterpret_cast<const float4*>(hp);
            float4 v1 = *reinterpret_cast<const float4*>(hp + 4);
            uint4 pk;
            pk.x = pack2(v0.x, v0.y); pk.y = pack2(v0.z, v0.w);
            pk.z = pack2(v1.x, v1.y); pk.w = pack2(v1.z, v1.w);
            int off = (b * 256 + r8 * 2) ^ ((b & 7) << 4);
            *reinterpret_cast<uint4*>(&sH[0][0] + off) = pk;
        }
        int roff[4], woff[4], uoff[4];
#pragma unroll
        for (int kf = 0; kf < 4; ++kf)
            roff[kf] = (l15 * 256 + kf * 64 + g * 16) ^ ((l15 & 7) << 4);
#pragma unroll
        for (int mm = 0; mm < 4; ++mm) {
            woff[mm] = (l15 * 256 + (64 * wid + mm * 16 + g * 4) * 2) ^ ((l15 & 7) << 4);
            uoff[mm] = (16 * wid + 4 * mm + g) * 256 + l15 * 16;
        }
        SYNC_LDS();

        for (int K = 0; K < Tm; ++K) {
            int cur = K & 1;
            const char* ub = &sU[K & 7][0];
            f32x4 acc[4], acc2[4];
#pragma unroll
            for (int mm = 0; mm < 4; ++mm) {
                acc[mm] = *reinterpret_cast<const f32x4*>(ub + uoff[mm]);
                acc2[mm] = (f32x4){0.f, 0.f, 0.f, 0.f};
            }
            bf16x8 Bf[4];
#pragma unroll
            for (int kf = 0; kf < 4; ++kf)
                Bf[kf] = *reinterpret_cast<const bf16x8*>(&sH[cur][0] + roff[kf]);
#pragma unroll
            for (int mm = 0; mm < 4; ++mm) {
                acc[mm] = __builtin_amdgcn_mfma_f32_16x16x32_bf16(
                    Af[mm][0], Bf[0], acc[mm], 0, 0, 0);
                acc2[mm] = __builtin_amdgcn_mfma_f32_16x16x32_bf16(
                    Af[mm][2], Bf[2], acc2[mm], 0, 0, 0);
                acc[mm] = __builtin_amdgcn_mfma_f32_16x16x32_bf16(
                    Af[mm][1], Bf[1], acc[mm], 0, 0, 0);
                acc2[mm] = __builtin_amdgcn_mfma_f32_16x16x32_bf16(
                    Af[mm][3], Bf[3], acc2[mm], 0, 0, 0);
            }
#pragma unroll
            for (int mm = 0; mm < 4; ++mm) {
                acc[mm] += acc2[mm];
                bf16x4 pk;
                pk[0] = (__bf16)acc[mm][0]; pk[1] = (__bf16)acc[mm][1];
                pk[2] = (__bf16)acc[mm][2]; pk[3] = (__bf16)acc[mm][3];
                *reinterpret_cast<bf16x4*>(&sH[cur ^ 1][0] + woff[mm]) = pk;
            }
            SYNC_LDS();
        }
    } else if (wid == 2) {
        // ================= u producer =================
        const float* ubase = xwb + (size_t)(b0 + l15) * MHW + mi * HH + g * 4;
#pragma unroll
        for (int q = 0; q < 4; ++q) {  // prologue: slots 0..3
            int t = min(q, Tm - 1) << mi;
            const float* pt = ubase + (size_t)t * BB * MHW;
#pragma unroll
            for (int p = 0; p < 8; ++p)
                gld_lds16(pt + p * 16, &sU[q][0] + p * 1024);
        }
        SYNC_VM24();  // retires slot 0
        for (int K = 0; K < Tm; ++K) {
            int t = min(K + 4, Tm - 1) << mi;
            int slot = (K + 4) & 7;
            const float* pt = ubase + (size_t)t * BB * MHW;
#pragma unroll
            for (int p = 0; p < 8; ++p)
                gld_lds16(pt + p * 16, &sU[slot][0] + p * 1024);
            SYNC_VM24();  // retires slot K+1 (needed next step)
        }
        asm volatile("s_waitcnt vmcnt(0)" ::: "memory");
    } else {
        // ================= h storer =================
        int bq = lane >> 2;
        int rr = (lane & 3) * 32;
        unsigned short* hm =
            hmod + c_hmod_off[mi] + (size_t)(b0 + bq) * HH + rr;
        int soff[4];
#pragma unroll
        for (int c = 0; c < 4; ++c)
            soff[c] = (bq * 256 + (rr + c * 8) * 2) ^ ((bq & 7) << 4);
        SYNC_LDS();
        for (int K = 0; K < Tm; ++K) {
            if (K >= 1) {
                uint4 h[4];
#pragma unroll
                for (int c = 0; c < 4; ++c)
                    h[c] = *reinterpret_cast<const uint4*>(&sH[K & 1][0] + soff[c]);
                unsigned short* dst = hm + (size_t)(K - 1) * BB * HH;
#pragma unroll
                for (int c = 0; c < 4; ++c)
                    *reinterpret_cast<uint4*>(dst + c * 8) = h[c];
            }
            SYNC_LDS();
        }
        {  // final state s_Tm -> hmod[Tm-1]
            uint4 h[4];
#pragma unroll
            for (int c = 0; c < 4; ++c)
                h[c] = *reinterpret_cast<const uint4*>(&sH[Tm & 1][0] + soff[c]);
            unsigned short* dst = hm + (size_t)(Tm - 1) * BB * HH;
#pragma unroll
            for (int c = 0; c < 4; ++c)
                *reinterpret_cast<uint4*>(dst + c * 8) = h[c];
        }
    }
}

// ---------------------------------------------------------------------------
// K_out: out[t][b][j*H + h] = bf2f(Hmod[j][t>>j][b][h]); h_last for t==T-1
// ---------------------------------------------------------------------------
__global__ __launch_bounds__(256) void k_out(const unsigned short* __restrict__ hmod,
                                             float* __restrict__ out) {
    int b = blockIdx.x, t = blockIdx.y;
    int tid = threadIdx.x;
    int i = tid * 4;
    int j = i >> 7;
    int k = t >> j;
    ushort4 h = *reinterpret_cast<const ushort4*>(
        &hmod[c_hmod_off[j] + ((size_t)k * BB + b) * HH + (i & 127)]);
    float4 v = make_float4(bf2f(h.x), bf2f(h.y), bf2f(h.z), bf2f(h.w));
    *reinterpret_cast<float4*>(&out[((size_t)t * BB + b) * MHW + i]) = v;
    if (t == TT - 1) {
        *reinterpret_cast<float4*>(
            &out[(size_t)TT * BB * MHW + (size_t)b * MHW + i]) = v;
    }
}

// ---------------------------------------------------------------------------
extern "C" void kernel_launch(void* const* d_in, const int* in_sizes, int n_in,
                              void* d_out, int out_size, void* d_ws, size_t ws_size,
                              hipStream_t stream) {
    const float* x = (const float*)d_in[0];
    const float* hprev = (const float*)d_in[1];
    const float* Wxh = (const float*)d_in[2];
    const float* Whh = (const float*)d_in[3];
    const float* bh = (const float*)d_in[4];
    float* out = (float*)d_out;

    float* xwb = out;                              // scratch in d_out
    unsigned short* hmod = (unsigned short*)d_ws;  // bf16, 16.7 MB

    k_xw<<<dim3(1020), 256, 0, stream>>>(x, Wxh, bh, xwb);

    for (int mi = 7; mi >= 0; --mi) {
        if (mi < 7)
            k_u<<<dim3(TT >> mi), 256, 0, stream>>>(Whh, hprev, hmod, xwb, mi);
        k_phase<<<8, 256, 0, stream>>>(Whh, hprev, xwb, hmod, mi);
    }

    k_out<<<dim3(128, 256), 256, 0, stream>>>(hmod, out);
}